// Round 1
// baseline (89.082 us; speedup 1.0000x reference)
//
#include <hip/hip_runtime.h>

#define NB 2
#define NP 1024
#define NC 128
#define NG 7
#define NSM 48
#define BN (NB*NP)

#define OFF_ORIS 0
#define OFF_NORS (BN*3)
#define OFF_PUPS (2*BN*3)
#define OFF_POFF (OFF_PUPS + BN*16*3)
#define OFF_PU   (OFF_POFF + BN*3)

__device__ __forceinline__ void bnorm3(float v[3]) {
    float ss = __fadd_rn(__fadd_rn(__fmul_rn(v[0],v[0]), __fmul_rn(v[1],v[1])), __fmul_rn(v[2],v[2]));
    float nr = sqrtf(__fadd_rn(ss, 1e-8f));
    float dn = __fadd_rn(nr, 1e-10f);
    v[0] = __fdiv_rn(v[0], dn);
    v[1] = __fdiv_rn(v[1], dn);
    v[2] = __fdiv_rn(v[2], dn);
}

// Kernel 1: one wave per point. oris/nors (outputs) + rot frame + pts + |pts|^2 (workspace).
__global__ __launch_bounds__(64) void k1(const float* __restrict__ xyz,
                                         const float* __restrict__ feat,
                                         const float* __restrict__ W0, const float* __restrict__ b0,
                                         const float* __restrict__ W1, const float* __restrict__ b1,
                                         float* __restrict__ out,
                                         float* __restrict__ pts_ws,
                                         float* __restrict__ nrm_ws,
                                         float* __restrict__ rot_ws) {
    int p = blockIdx.x;
    int b = p >> 10, n = p & (NP - 1);
    int l = threadIdx.x;

    float f0 = feat[p*NC + l];
    float f1 = feat[p*NC + 64 + l];
    float s0 = f0*W0[l]     + f1*W0[64+l];
    float s1 = f0*W0[128+l] + f1*W0[192+l];
    float s2 = f0*W0[256+l] + f1*W0[320+l];
    float s3 = f0*W1[l]     + f1*W1[64+l];
    float s4 = f0*W1[128+l] + f1*W1[192+l];
    float s5 = f0*W1[256+l] + f1*W1[320+l];
    for (int off = 32; off; off >>= 1) {
        s0 += __shfl_xor(s0, off);
        s1 += __shfl_xor(s1, off);
        s2 += __shfl_xor(s2, off);
        s3 += __shfl_xor(s3, off);
        s4 += __shfl_xor(s4, off);
        s5 += __shfl_xor(s5, off);
    }
    if (l == 0) {
        float o[3]  = { s0 + b0[0], s1 + b0[1], s2 + b0[2] };
        float nn[3] = { s3 + b1[0], s4 + b1[1], s5 + b1[2] };
        bnorm3(o);
        bnorm3(nn);
        // ori_rot90 = bn(cross(oris, nors))
        float r90[3];
        r90[0] = __fsub_rn(__fmul_rn(o[1], nn[2]), __fmul_rn(o[2], nn[1]));
        r90[1] = __fsub_rn(__fmul_rn(o[2], nn[0]), __fmul_rn(o[0], nn[2]));
        r90[2] = __fsub_rn(__fmul_rn(o[0], nn[1]), __fmul_rn(o[1], nn[0]));
        bnorm3(r90);
        // ori_0 = bn(cross(ori_rot90, nors))
        float o0[3];
        o0[0] = __fsub_rn(__fmul_rn(r90[1], nn[2]), __fmul_rn(r90[2], nn[1]));
        o0[1] = __fsub_rn(__fmul_rn(r90[2], nn[0]), __fmul_rn(r90[0], nn[2]));
        o0[2] = __fsub_rn(__fmul_rn(r90[0], nn[1]), __fmul_rn(r90[1], nn[0]));
        bnorm3(o0);

        out[OFF_ORIS + p*3+0] = o[0];  out[OFF_ORIS + p*3+1] = o[1];  out[OFF_ORIS + p*3+2] = o[2];
        out[OFF_NORS + p*3+0] = nn[0]; out[OFF_NORS + p*3+1] = nn[1]; out[OFF_NORS + p*3+2] = nn[2];

        // rot_ws[p*9 + v*3 + c] = vec_v[c]; v: 0=ori_0, 1=ori_rot90, 2=nors
        rot_ws[p*9+0] = o0[0];  rot_ws[p*9+1] = o0[1];  rot_ws[p*9+2] = o0[2];
        rot_ws[p*9+3] = r90[0]; rot_ws[p*9+4] = r90[1]; rot_ws[p*9+5] = r90[2];
        rot_ws[p*9+6] = nn[0];  rot_ws[p*9+7] = nn[1];  rot_ws[p*9+8] = nn[2];

        float px = xyz[(b*3+0)*NP + n];
        float py = xyz[(b*3+1)*NP + n];
        float pz = xyz[(b*3+2)*NP + n];
        pts_ws[p*3+0] = px; pts_ws[p*3+1] = py; pts_ws[p*3+2] = pz;
        nrm_ws[p] = __fadd_rn(__fadd_rn(__fmul_rn(px,px), __fmul_rn(py,py)), __fmul_rn(pz,pz));
    }
}

// Kernel 2: one block (256 thr) per point. Neighbor search + sparse grid conv + up-projection.
__global__ __launch_bounds__(256) void k2(const float* __restrict__ feat,
                                          const float* __restrict__ W_unet,
                                          const int* __restrict__ index,
                                          const float* __restrict__ pts_ws,
                                          const float* __restrict__ nrm_ws,
                                          const float* __restrict__ rot_ws,
                                          float* __restrict__ out) {
    __shared__ float spts[NP*3];
    __shared__ float snrm[NP];
    __shared__ float srot[9];
    __shared__ int   sgidx[NSM];
    __shared__ int   sidx[NSM];
    __shared__ int   swin[NSM];
    __shared__ float sfo[NG*NG*3];
    __shared__ float spu[NG*NG*3];

    int p = blockIdx.x;
    int b = p >> 10, n = p & (NP - 1);
    int tid = threadIdx.x;

    for (int i = tid; i < NP*3; i += 256) spts[i] = pts_ws[b*NP*3 + i];
    for (int i = tid; i < NP; i += 256)   snrm[i] = nrm_ws[b*NP + i];
    if (tid < 9) srot[tid] = rot_ws[p*9 + tid];
    if (tid < NG*NG*3) sfo[tid] = 0.0f;
    __syncthreads();

    // --- ordered first-48 radius query (wave 0) ---
    if (tid < 64) {
        float cx = spts[n*3+0], cy = spts[n*3+1], cz = spts[n*3+2];
        float cn = snrm[n];
        int count = 0, first = -1;
        for (int base = 0; base < NP && count < NSM; base += 64) {
            int m = base + tid;
            float dot = __fadd_rn(__fadd_rn(__fmul_rn(cx, spts[m*3+0]),
                                            __fmul_rn(cy, spts[m*3+1])),
                                  __fmul_rn(cz, spts[m*3+2]));
            float d = __fadd_rn(__fadd_rn(__fmul_rn(-2.0f, dot), cn), snrm[m]);
            bool sel = !(d > 0.09f);
            unsigned long long mk = __ballot(sel);
            if (first < 0 && mk != 0ull) first = base + (__ffsll(mk) - 1);
            if (sel) {
                int pos = count + (int)__popcll(mk & ((1ull << tid) - 1ull));
                if (pos < NSM) sgidx[pos] = m;
            }
            count += (int)__popcll(mk);
        }
        if (first < 0) first = n;  // unreachable (self-dist == 0), safety
        if (count < NSM) {
            for (int i = count + tid; i < NSM; i += 64) sgidx[i] = first;
        }
    }
    __syncthreads();

    // --- per-sample grid cell index ---
    if (tid < NSM) {
        int m = sgidx[tid];
        float lx = spts[m*3+0] - spts[n*3+0];
        float ly = spts[m*3+1] - spts[n*3+1];
        float lz = spts[m*3+2] - spts[n*3+2];
        int c[3];
        #pragma unroll
        for (int dd = 0; dd < 3; ++dd) {
            float lp = __fadd_rn(__fadd_rn(__fmul_rn(lx, srot[dd*3+0]),
                                           __fmul_rn(ly, srot[dd*3+1])),
                                 __fmul_rn(lz, srot[dd*3+2]));
            float t = rintf(__fmul_rn(__fdiv_rn(__fadd_rn(lp, 0.3f), 0.6f), 6.0f));
            int ci = (int)t;
            ci = ci < 0 ? 0 : (ci > 6 ? 6 : ci);
            c[dd] = ci;
        }
        sidx[tid] = c[0]*NG + c[1]*NG + c[2];
    }
    __syncthreads();

    // --- last-write-wins dedup: winner = largest s with this cell ---
    if (tid < NSM) {
        int w = 1, my = sidx[tid];
        for (int s2 = tid + 1; s2 < NSM; ++s2)
            if (sidx[s2] == my) { w = 0; break; }
        swin[tid] = w;
    }
    __syncthreads();

    // --- sparse feat_off accumulation: one wave per sample slot ---
    {
        int wid = tid >> 6, lane = tid & 63;
        for (int s = wid; s < NSM; s += 4) {
            if (!swin[s]) continue;
            int cell = sidx[s];
            int k = cell % NG;
            int q = cell / NG;          // i*7 + j
            int m = sgidx[s];
            const float* fr = feat + (size_t)(b*NP + m) * NC;
            float p0 = 0.f, p1 = 0.f, p2 = 0.f;
            #pragma unroll
            for (int cc = lane; cc < NC; cc += 64) {
                float f = fr[cc];
                const float* w = W_unet + cc*(NG*3) + k*3;
                p0 += f * w[0];
                p1 += f * w[1];
                p2 += f * w[2];
            }
            for (int off = 32; off; off >>= 1) {
                p0 += __shfl_xor(p0, off);
                p1 += __shfl_xor(p1, off);
                p2 += __shfl_xor(p2, off);
            }
            if (lane == 0) {
                atomicAdd(&sfo[q*3+0], p0);
                atomicAdd(&sfo[q*3+1], p1);
                atomicAdd(&sfo[q*3+2], p2);
            }
        }
    }
    __syncthreads();

    // --- up-projection + pts_up outputs ---
    if (tid < NG*NG*3) {
        int q = tid / 3, d = tid % 3;
        int qi = q / NG, qj = q % NG;
        float v0 = (float)((-30 + 10*qi) * 0.01);
        float v1 = (float)((-30 + 10*qj) * 0.01);
        float u0 = __fadd_rn(v0, sfo[q*3+0]);
        float u1 = __fadd_rn(v1, sfo[q*3+1]);
        float u2 = sfo[q*3+2]; // vals[...,2] == 0
        // pts_up[q][d] = ((u0*vec0[d] + u1*vec1[d]) + u2*vec2[d]) + center[d]
        float r = __fadd_rn(
                    __fadd_rn(
                      __fadd_rn(__fmul_rn(u0, srot[0*3+d]), __fmul_rn(u1, srot[1*3+d])),
                      __fmul_rn(u2, srot[2*3+d])),
                    spts[n*3+d]);
        spu[tid] = r;
        out[OFF_PU + p*(NG*NG*3) + tid] = r;
        if (q == 24) out[OFF_POFF + p*3 + d] = r;
    }
    __syncthreads();

    if (tid < 16*3) {
        int t = tid / 3, d = tid % 3;
        int q = index[t];
        out[OFF_PUPS + (p*16 + t)*3 + d] = spu[q*3 + d];
    }
}

extern "C" void kernel_launch(void* const* d_in, const int* in_sizes, int n_in,
                              void* d_out, int out_size, void* d_ws, size_t ws_size,
                              hipStream_t stream) {
    const float* xyz    = (const float*)d_in[0];
    const float* feat   = (const float*)d_in[1];
    const float* W0     = (const float*)d_in[2];
    const float* b0     = (const float*)d_in[3];
    const float* W1     = (const float*)d_in[4];
    const float* b1     = (const float*)d_in[5];
    const float* W_unet = (const float*)d_in[6];
    const int*   index  = (const int*)d_in[7];
    float* out = (float*)d_out;
    float* ws  = (float*)d_ws;

    float* pts_ws = ws;                      // BN*3
    float* nrm_ws = ws + BN*3;               // BN
    float* rot_ws = ws + BN*3 + BN;          // BN*9

    hipLaunchKernelGGL(k1, dim3(BN), dim3(64), 0, stream,
                       xyz, feat, W0, b0, W1, b1, out, pts_ws, nrm_ws, rot_ws);
    hipLaunchKernelGGL(k2, dim3(BN), dim3(256), 0, stream,
                       feat, W_unet, index, pts_ws, nrm_ws, rot_ws, out);
}

// Round 2
// 78.804 us; speedup vs baseline: 1.1304x; 1.1304x over previous
//
#include <hip/hip_runtime.h>

#define NB 2
#define NP 1024
#define NC 128
#define NG 7
#define NSM 48
#define BN (NB*NP)

#define OFF_ORIS 0
#define OFF_NORS (BN*3)
#define OFF_PUPS (2*BN*3)
#define OFF_POFF (OFF_PUPS + BN*16*3)
#define OFF_PU   (OFF_POFF + BN*3)

__device__ __forceinline__ void bnorm3(float v[3]) {
    float ss = __fadd_rn(__fadd_rn(__fmul_rn(v[0],v[0]), __fmul_rn(v[1],v[1])), __fmul_rn(v[2],v[2]));
    float nr = sqrtf(__fadd_rn(ss, 1e-8f));
    float dn = __fadd_rn(nr, 1e-10f);
    v[0] = __fdiv_rn(v[0], dn);
    v[1] = __fdiv_rn(v[1], dn);
    v[2] = __fdiv_rn(v[2], dn);
}

// Fully fused: one block (256 thr) per point.
// Wave 0: 128-feat matvec -> oris/nors/rot.  Waves 1-3: stage pts+|pts|^2 from xyz.
// Then: 4-wave parallel radius ballot -> bitmap -> ordered first-48 extraction,
// cell idx + last-write-wins dedup, 16-lane-per-sample feat_off dots, up-projection.
__global__ __launch_bounds__(256) void kfused(const float* __restrict__ xyz,
                                              const float* __restrict__ feat,
                                              const float* __restrict__ W0, const float* __restrict__ b0,
                                              const float* __restrict__ W1, const float* __restrict__ b1,
                                              const float* __restrict__ W_unet,
                                              const int* __restrict__ index,
                                              float* __restrict__ out) {
    __shared__ float spts[NP*3];
    __shared__ float snrm[NP];
    __shared__ float srot[9];
    __shared__ unsigned long long smask[16];
    __shared__ int   sgidx[NSM];
    __shared__ int   sidx[NSM];
    __shared__ int   swin[NSM];
    __shared__ int   scnt;
    __shared__ float sfo[NG*NG*3];
    __shared__ float spu[NG*NG*3];

    int p = blockIdx.x;
    int b = p >> 10, n = p & (NP - 1);
    int tid = threadIdx.x;
    int w = tid >> 6, l = tid & 63;

    if (tid < NG*NG*3) sfo[tid] = 0.0f;

    if (w == 0) {
        // ---- matvec + rot frame (this point only) ----
        float f0 = feat[p*NC + l];
        float f1 = feat[p*NC + 64 + l];
        float s0 = f0*W0[l]     + f1*W0[64+l];
        float s1 = f0*W0[128+l] + f1*W0[192+l];
        float s2 = f0*W0[256+l] + f1*W0[320+l];
        float s3 = f0*W1[l]     + f1*W1[64+l];
        float s4 = f0*W1[128+l] + f1*W1[192+l];
        float s5 = f0*W1[256+l] + f1*W1[320+l];
        for (int off = 32; off; off >>= 1) {
            s0 += __shfl_xor(s0, off);
            s1 += __shfl_xor(s1, off);
            s2 += __shfl_xor(s2, off);
            s3 += __shfl_xor(s3, off);
            s4 += __shfl_xor(s4, off);
            s5 += __shfl_xor(s5, off);
        }
        if (l == 0) {
            float o[3]  = { s0 + b0[0], s1 + b0[1], s2 + b0[2] };
            float nn[3] = { s3 + b1[0], s4 + b1[1], s5 + b1[2] };
            bnorm3(o);
            bnorm3(nn);
            float r90[3];
            r90[0] = __fsub_rn(__fmul_rn(o[1], nn[2]), __fmul_rn(o[2], nn[1]));
            r90[1] = __fsub_rn(__fmul_rn(o[2], nn[0]), __fmul_rn(o[0], nn[2]));
            r90[2] = __fsub_rn(__fmul_rn(o[0], nn[1]), __fmul_rn(o[1], nn[0]));
            bnorm3(r90);
            float o0[3];
            o0[0] = __fsub_rn(__fmul_rn(r90[1], nn[2]), __fmul_rn(r90[2], nn[1]));
            o0[1] = __fsub_rn(__fmul_rn(r90[2], nn[0]), __fmul_rn(r90[0], nn[2]));
            o0[2] = __fsub_rn(__fmul_rn(r90[0], nn[1]), __fmul_rn(r90[1], nn[0]));
            bnorm3(o0);

            out[OFF_ORIS + p*3+0] = o[0];  out[OFF_ORIS + p*3+1] = o[1];  out[OFF_ORIS + p*3+2] = o[2];
            out[OFF_NORS + p*3+0] = nn[0]; out[OFF_NORS + p*3+1] = nn[1]; out[OFF_NORS + p*3+2] = nn[2];

            srot[0] = o0[0];  srot[1] = o0[1];  srot[2] = o0[2];
            srot[3] = r90[0]; srot[4] = r90[1]; srot[5] = r90[2];
            srot[6] = nn[0];  srot[7] = nn[1];  srot[8] = nn[2];
        }
    } else {
        // ---- stage pts + norms straight from xyz (waves 1-3) ----
        const float* xb = xyz + (size_t)b*3*NP;
        for (int j = tid - 64; j < NP; j += 192) {
            float px = xb[j];
            float py = xb[NP + j];
            float pz = xb[2*NP + j];
            spts[j*3+0] = px; spts[j*3+1] = py; spts[j*3+2] = pz;
            snrm[j] = __fadd_rn(__fadd_rn(__fmul_rn(px,px), __fmul_rn(py,py)), __fmul_rn(pz,pz));
        }
    }
    __syncthreads();

    // ---- radius ballots: wave w covers chunks 4w..4w+3 ----
    {
        float cx = spts[n*3+0], cy = spts[n*3+1], cz = spts[n*3+2];
        float cn = snrm[n];
        #pragma unroll
        for (int k = 0; k < 4; ++k) {
            int m = ((w<<2) + k)*64 + l;
            float dot = __fadd_rn(__fadd_rn(__fmul_rn(cx, spts[m*3+0]),
                                            __fmul_rn(cy, spts[m*3+1])),
                                  __fmul_rn(cz, spts[m*3+2]));
            float d = __fadd_rn(__fadd_rn(__fmul_rn(-2.0f, dot), cn), snrm[m]);
            bool sel = !(d > 0.09f);
            unsigned long long mk = __ballot(sel);
            if (l == 0) smask[(w<<2) + k] = mk;
        }
    }
    __syncthreads();

    // ---- ordered first-48 extraction (16 lanes of wave 0) ----
    if (tid < 16) {
        unsigned long long wv = smask[tid];
        int prefix = 0, total = 0;
        #pragma unroll
        for (int j = 0; j < 16; ++j) {
            int pc = __popcll(smask[j]);
            if (j < tid) prefix += pc;
            total += pc;
        }
        if (tid == 0) scnt = total;
        int pos = prefix;
        while (wv && pos < NSM) {
            int bpos = __ffsll(wv) - 1;
            sgidx[pos++] = (tid << 6) + bpos;
            wv &= wv - 1;
        }
    }
    __syncthreads();

    // ---- pad with first selected index ----
    {
        int total = scnt;
        if (tid < NSM && tid >= total) sgidx[tid] = sgidx[0];
    }
    __syncthreads();

    // ---- per-sample grid cell ----
    if (tid < NSM) {
        int m = sgidx[tid];
        float lx = spts[m*3+0] - spts[n*3+0];
        float ly = spts[m*3+1] - spts[n*3+1];
        float lz = spts[m*3+2] - spts[n*3+2];
        int c[3];
        #pragma unroll
        for (int dd = 0; dd < 3; ++dd) {
            float lp = __fadd_rn(__fadd_rn(__fmul_rn(lx, srot[dd*3+0]),
                                           __fmul_rn(ly, srot[dd*3+1])),
                                 __fmul_rn(lz, srot[dd*3+2]));
            float t = rintf(__fmul_rn(__fdiv_rn(__fadd_rn(lp, 0.3f), 0.6f), 6.0f));
            int ci = (int)t;
            ci = ci < 0 ? 0 : (ci > 6 ? 6 : ci);
            c[dd] = ci;
        }
        sidx[tid] = c[0]*NG + c[1]*NG + c[2];
    }
    __syncthreads();

    // ---- last-write-wins dedup ----
    if (tid < NSM) {
        int win = 1, my = sidx[tid];
        for (int s2 = tid + 1; s2 < NSM; ++s2)
            if (sidx[s2] == my) { win = 0; break; }
        swin[tid] = win;
    }
    __syncthreads();

    // ---- feat_off: 16 lanes per sample, 16 samples per pass, 3 passes ----
    {
        int sl = tid & 15;
        int sg = tid >> 4;   // 0..15
        #pragma unroll
        for (int r = 0; r < 3; ++r) {
            int s = r*16 + sg;
            int act = swin[s];
            int q = 0, k = 0;
            float p0 = 0.f, p1 = 0.f, p2 = 0.f;
            if (act) {
                int cell = sidx[s];
                k = cell % NG;
                q = cell / NG;
                const float* fr = feat + (size_t)(b*NP + sgidx[s]) * NC;
                #pragma unroll
                for (int c8 = 0; c8 < 8; ++c8) {
                    int cc = sl + c8*16;
                    float f = fr[cc];
                    const float* wp = W_unet + cc*(NG*3) + k*3;
                    p0 += f * wp[0];
                    p1 += f * wp[1];
                    p2 += f * wp[2];
                }
            }
            #pragma unroll
            for (int off = 8; off; off >>= 1) {
                p0 += __shfl_xor(p0, off);
                p1 += __shfl_xor(p1, off);
                p2 += __shfl_xor(p2, off);
            }
            if (act && sl == 0) {
                atomicAdd(&sfo[q*3+0], p0);
                atomicAdd(&sfo[q*3+1], p1);
                atomicAdd(&sfo[q*3+2], p2);
            }
        }
    }
    __syncthreads();

    // ---- up-projection + outputs ----
    if (tid < NG*NG*3) {
        int q = tid / 3, d = tid % 3;
        int qi = q / NG, qj = q % NG;
        float v0 = (float)((-30 + 10*qi) * 0.01);
        float v1 = (float)((-30 + 10*qj) * 0.01);
        float u0 = __fadd_rn(v0, sfo[q*3+0]);
        float u1 = __fadd_rn(v1, sfo[q*3+1]);
        float u2 = sfo[q*3+2];
        float r = __fadd_rn(
                    __fadd_rn(
                      __fadd_rn(__fmul_rn(u0, srot[0*3+d]), __fmul_rn(u1, srot[1*3+d])),
                      __fmul_rn(u2, srot[2*3+d])),
                    spts[n*3+d]);
        spu[tid] = r;
        out[OFF_PU + p*(NG*NG*3) + tid] = r;
        if (q == 24) out[OFF_POFF + p*3 + d] = r;
    }
    __syncthreads();

    if (tid < 16*3) {
        int t = tid / 3, d = tid % 3;
        int q = index[t];
        out[OFF_PUPS + (p*16 + t)*3 + d] = spu[q*3 + d];
    }
}

extern "C" void kernel_launch(void* const* d_in, const int* in_sizes, int n_in,
                              void* d_out, int out_size, void* d_ws, size_t ws_size,
                              hipStream_t stream) {
    const float* xyz    = (const float*)d_in[0];
    const float* feat   = (const float*)d_in[1];
    const float* W0     = (const float*)d_in[2];
    const float* b0     = (const float*)d_in[3];
    const float* W1     = (const float*)d_in[4];
    const float* b1     = (const float*)d_in[5];
    const float* W_unet = (const float*)d_in[6];
    const int*   index  = (const int*)d_in[7];
    float* out = (float*)d_out;

    hipLaunchKernelGGL(kfused, dim3(BN), dim3(256), 0, stream,
                       xyz, feat, W0, b0, W1, b1, W_unet, index, out);
}

// Round 5
// 78.623 us; speedup vs baseline: 1.1330x; 1.0023x over previous
//
#include <hip/hip_runtime.h>

#define NB 2
#define NP 1024
#define NC 128
#define NG 7
#define NSM 48
#define BN (NB*NP)

#define OFF_ORIS 0
#define OFF_NORS (BN*3)
#define OFF_PUPS (2*BN*3)
#define OFF_POFF (OFF_PUPS + BN*16*3)
#define OFF_PU   (OFF_POFF + BN*3)

__device__ __forceinline__ void bnorm3(float v[3]) {
    float ss = __fadd_rn(__fadd_rn(__fmul_rn(v[0],v[0]), __fmul_rn(v[1],v[1])), __fmul_rn(v[2],v[2]));
    float nr = sqrtf(__fadd_rn(ss, 1e-8f));
    float dn = __fadd_rn(nr, 1e-10f);
    v[0] = __fdiv_rn(v[0], dn);
    v[1] = __fdiv_rn(v[1], dn);
    v[2] = __fdiv_rn(v[2], dn);
}

// One block (256 thr) per point. No LDS point-cloud staging: xyz is 24 KB and
// L1-resident, so ballot/cell/upproj read it straight from global. 5 barriers.
__global__ __launch_bounds__(256) void kfused(const float* __restrict__ xyz,
                                              const float* __restrict__ feat,
                                              const float* __restrict__ W0, const float* __restrict__ b0,
                                              const float* __restrict__ W1, const float* __restrict__ b1,
                                              const float* __restrict__ W_unet,
                                              const int* __restrict__ index,
                                              float* __restrict__ out) {
    __shared__ float srot[9];
    __shared__ unsigned long long smask[16];
    __shared__ int   sgidx[NSM];
    __shared__ int   sidx[NSM];
    __shared__ int   scell[91];        // cell idx = 7*c0 + 7*c1 + c2 <= 90
    __shared__ float sfo[NG*NG*3];
    __shared__ float spu[NG*NG*3];

    int p = blockIdx.x;
    int b = p >> 10, n = p & (NP - 1);
    int tid = threadIdx.x;
    int w = tid >> 6, l = tid & 63;
    const float* xb = xyz + (size_t)b*3*NP;

    if (tid < NG*NG*3) sfo[tid] = 0.0f;
    if (tid < 91)      scell[tid] = -1;

    // center point (uniform across block -> scalarized)
    float cx = xb[n], cy = xb[NP + n], cz = xb[2*NP + n];
    float cn = __fadd_rn(__fadd_rn(__fmul_rn(cx,cx), __fmul_rn(cy,cy)), __fmul_rn(cz,cz));

    // ---- matvec (wave 0) overlapped with radius ballots (chunk 0 on wave 0 after matvec,
    //      chunks 1..15 on waves 1..3) ----
    if (w == 0) {
        float f0 = feat[p*NC + l];
        float f1 = feat[p*NC + 64 + l];
        float s0 = f0*W0[l]     + f1*W0[64+l];
        float s1 = f0*W0[128+l] + f1*W0[192+l];
        float s2 = f0*W0[256+l] + f1*W0[320+l];
        float s3 = f0*W1[l]     + f1*W1[64+l];
        float s4 = f0*W1[128+l] + f1*W1[192+l];
        float s5 = f0*W1[256+l] + f1*W1[320+l];
        for (int off = 32; off; off >>= 1) {
            s0 += __shfl_xor(s0, off);
            s1 += __shfl_xor(s1, off);
            s2 += __shfl_xor(s2, off);
            s3 += __shfl_xor(s3, off);
            s4 += __shfl_xor(s4, off);
            s5 += __shfl_xor(s5, off);
        }
        if (l == 0) {
            float o[3]  = { s0 + b0[0], s1 + b0[1], s2 + b0[2] };
            float nn[3] = { s3 + b1[0], s4 + b1[1], s5 + b1[2] };
            bnorm3(o);
            bnorm3(nn);
            float r90[3];
            r90[0] = __fsub_rn(__fmul_rn(o[1], nn[2]), __fmul_rn(o[2], nn[1]));
            r90[1] = __fsub_rn(__fmul_rn(o[2], nn[0]), __fmul_rn(o[0], nn[2]));
            r90[2] = __fsub_rn(__fmul_rn(o[0], nn[1]), __fmul_rn(o[1], nn[0]));
            bnorm3(r90);
            float o0[3];
            o0[0] = __fsub_rn(__fmul_rn(r90[1], nn[2]), __fmul_rn(r90[2], nn[1]));
            o0[1] = __fsub_rn(__fmul_rn(r90[2], nn[0]), __fmul_rn(r90[0], nn[2]));
            o0[2] = __fsub_rn(__fmul_rn(r90[0], nn[1]), __fmul_rn(r90[1], nn[0]));
            bnorm3(o0);

            out[OFF_ORIS + p*3+0] = o[0];  out[OFF_ORIS + p*3+1] = o[1];  out[OFF_ORIS + p*3+2] = o[2];
            out[OFF_NORS + p*3+0] = nn[0]; out[OFF_NORS + p*3+1] = nn[1]; out[OFF_NORS + p*3+2] = nn[2];

            srot[0] = o0[0];  srot[1] = o0[1];  srot[2] = o0[2];
            srot[3] = r90[0]; srot[4] = r90[1]; srot[5] = r90[2];
            srot[6] = nn[0];  srot[7] = nn[1];  srot[8] = nn[2];
        }
        // wave 0 handles ballot chunk 0
        {
            int m = l;
            float mx = xb[m], my = xb[NP + m], mz = xb[2*NP + m];
            float mn = __fadd_rn(__fadd_rn(__fmul_rn(mx,mx), __fmul_rn(my,my)), __fmul_rn(mz,mz));
            float dot = __fadd_rn(__fadd_rn(__fmul_rn(cx,mx), __fmul_rn(cy,my)), __fmul_rn(cz,mz));
            float d = __fadd_rn(__fadd_rn(__fmul_rn(-2.0f, dot), cn), mn);
            unsigned long long mk = __ballot(!(d > 0.09f));
            if (l == 0) smask[0] = mk;
        }
    } else {
        int ch0 = (w - 1) * 5 + 1;   // waves 1,2,3 -> chunks 1-5, 6-10, 11-15
        #pragma unroll
        for (int k = 0; k < 5; ++k) {
            int ch = ch0 + k;
            int m = (ch << 6) + l;
            float mx = xb[m], my = xb[NP + m], mz = xb[2*NP + m];
            float mn = __fadd_rn(__fadd_rn(__fmul_rn(mx,mx), __fmul_rn(my,my)), __fmul_rn(mz,mz));
            float dot = __fadd_rn(__fadd_rn(__fmul_rn(cx,mx), __fmul_rn(cy,my)), __fmul_rn(cz,mz));
            float d = __fadd_rn(__fadd_rn(__fmul_rn(-2.0f, dot), cn), mn);
            unsigned long long mk = __ballot(!(d > 0.09f));
            if (l == 0) smask[ch] = mk;
        }
    }
    __syncthreads();   // B1: smask + srot ready

    // ---- ordered first-48 extraction + pad (16 lanes) ----
    if (tid < 16) {
        unsigned long long wv = smask[tid];
        int prefix = 0, total = 0, firstj = 0;
        bool seen = false;
        #pragma unroll
        for (int j = 0; j < 16; ++j) {
            int pc = __popcll(smask[j]);
            if (j < tid) prefix += pc;
            if (!seen && pc) { firstj = j; seen = true; }
            total += pc;
        }
        int pos = prefix;
        while (wv && pos < NSM) {
            int bpos = __ffsll(wv) - 1;
            sgidx[pos++] = (tid << 6) + bpos;
            wv &= wv - 1;
        }
        if (total < NSM) {
            int first = (firstj << 6) + (__ffsll(smask[firstj]) - 1);
            for (int q2 = total + tid; q2 < NSM; q2 += 16) sgidx[q2] = first;
        }
    }
    __syncthreads();   // B2: sgidx ready

    // ---- per-sample cell + last-write-wins owner via atomicMax ----
    if (tid < NSM) {
        int m = sgidx[tid];
        float lx = __fsub_rn(xb[m],        cx);
        float ly = __fsub_rn(xb[NP + m],   cy);
        float lz = __fsub_rn(xb[2*NP + m], cz);
        int c[3];
        #pragma unroll
        for (int dd = 0; dd < 3; ++dd) {
            float lp = __fadd_rn(__fadd_rn(__fmul_rn(lx, srot[dd*3+0]),
                                           __fmul_rn(ly, srot[dd*3+1])),
                                 __fmul_rn(lz, srot[dd*3+2]));
            float t = rintf(__fmul_rn(__fdiv_rn(__fadd_rn(lp, 0.3f), 0.6f), 6.0f));
            int ci = (int)t;
            ci = ci < 0 ? 0 : (ci > 6 ? 6 : ci);
            c[dd] = ci;
        }
        int cell = c[0]*NG + c[1]*NG + c[2];
        sidx[tid] = cell;
        atomicMax(&scell[cell], tid);
    }
    __syncthreads();   // B3: owners ready

    // ---- feat_off: 16 lanes per sample, 16 samples per pass, 3 passes ----
    {
        int sl = tid & 15;
        int sg = tid >> 4;
        #pragma unroll
        for (int r = 0; r < 3; ++r) {
            int s = r*16 + sg;
            int cell = sidx[s];
            if (scell[cell] == s) {        // group-uniform predicate
                int k = cell % NG;
                int q = cell / NG;
                const float* fr = feat + (size_t)(b*NP + sgidx[s]) * NC;
                float p0 = 0.f, p1 = 0.f, p2 = 0.f;
                #pragma unroll
                for (int c8 = 0; c8 < 8; ++c8) {
                    int cc = sl + c8*16;
                    float f = fr[cc];
                    const float* wp = W_unet + cc*(NG*3) + k*3;
                    p0 += f * wp[0];
                    p1 += f * wp[1];
                    p2 += f * wp[2];
                }
                #pragma unroll
                for (int off = 8; off; off >>= 1) {
                    p0 += __shfl_xor(p0, off);
                    p1 += __shfl_xor(p1, off);
                    p2 += __shfl_xor(p2, off);
                }
                if (sl == 0) {
                    atomicAdd(&sfo[q*3+0], p0);
                    atomicAdd(&sfo[q*3+1], p1);
                    atomicAdd(&sfo[q*3+2], p2);
                }
            }
        }
    }
    __syncthreads();   // B4: sfo ready

    // ---- up-projection + outputs ----
    if (tid < NG*NG*3) {
        int q = tid / 3, d = tid % 3;
        int qi = q / NG, qj = q % NG;
        float v0 = (float)((-30 + 10*qi) * 0.01);
        float v1 = (float)((-30 + 10*qj) * 0.01);
        float u0 = __fadd_rn(v0, sfo[q*3+0]);
        float u1 = __fadd_rn(v1, sfo[q*3+1]);
        float u2 = sfo[q*3+2];
        float ctr = (d == 0) ? cx : (d == 1) ? cy : cz;
        float r = __fadd_rn(
                    __fadd_rn(
                      __fadd_rn(__fmul_rn(u0, srot[0*3+d]), __fmul_rn(u1, srot[1*3+d])),
                      __fmul_rn(u2, srot[2*3+d])),
                    ctr);
        spu[tid] = r;
        out[OFF_PU + p*(NG*NG*3) + tid] = r;
        if (q == 24) out[OFF_POFF + p*3 + d] = r;
    }
    __syncthreads();   // B5: spu ready

    if (tid < 16*3) {
        int t = tid / 3, d = tid % 3;
        int q = index[t];
        out[OFF_PUPS + (p*16 + t)*3 + d] = spu[q*3 + d];
    }
}

extern "C" void kernel_launch(void* const* d_in, const int* in_sizes, int n_in,
                              void* d_out, int out_size, void* d_ws, size_t ws_size,
                              hipStream_t stream) {
    const float* xyz    = (const float*)d_in[0];
    const float* feat   = (const float*)d_in[1];
    const float* W0     = (const float*)d_in[2];
    const float* b0     = (const float*)d_in[3];
    const float* W1     = (const float*)d_in[4];
    const float* b1     = (const float*)d_in[5];
    const float* W_unet = (const float*)d_in[6];
    const int*   index  = (const int*)d_in[7];
    float* out = (float*)d_out;

    hipLaunchKernelGGL(kfused, dim3(BN), dim3(256), 0, stream,
                       xyz, feat, W0, b0, W1, b1, W_unet, index, out);
}